// Round 19
// baseline (605.840 us; speedup 1.0000x reference)
//
#include <hip/hip_runtime.h>
#include <hip/hip_fp16.h>

#define Tt 512

typedef _Float16 f16x8 __attribute__((ext_vector_type(8)));
typedef float    f32x4 __attribute__((ext_vector_type(4)));

// Workspace byte offsets
#define BP16_OFF 0ul                              // fp16 B panel [1280][320] LINEAR
#define BP16_BYTES (2ul*1280*320)                 // 819,200
#define WHHM_OFF (BP16_OFF + BP16_BYTES)
#define WHHM_BYTES (16ul*2*10*4*5*64)             // 409,600 MFMA W fragments
#define BIAS_OFF (WHHM_OFF + WHHM_BYTES)
#define BIAS_BYTES (4ul*1280)
#define XG_OFF   (4ul*1024*1024)                  // fp16 xg [65536][1280] = 167.8 MB

__device__ __forceinline__ float sig2(float x) {
    return __builtin_amdgcn_rcpf(1.f + __builtin_amdgcn_exp2f(-1.442695041f * x));
}
__device__ __forceinline__ float tanh2(float x) {
    return 2.f * __builtin_amdgcn_rcpf(1.f + __builtin_amdgcn_exp2f(-2.885390082f * x)) - 1.f;
}

// ---------------- Kernel 0: pack weights (unchanged from R18) ----------------
__global__ void pack_weights(const float* __restrict__ Wih_f, const float* __restrict__ Whh_f,
                             const float* __restrict__ b_f,
                             const float* __restrict__ Wih_b, const float* __restrict__ Whh_b,
                             const float* __restrict__ b_b,
                             __half* __restrict__ Bp, uint4* __restrict__ Whhm,
                             float* __restrict__ bias_p) {
    int idx = blockIdx.x * 256 + threadIdx.x;
    const int T1 = 1280 * 320;
    const int T2 = 2 * 10 * 4 * 5 * 64;
    const int T3 = 1280;
    if (idx < T1) {
        int n = idx / 320, k = idx % 320;
        int dir = (n >= 640);
        int j2  = n - dir * 640;
        int u = j2 >> 2, q = j2 & 3;       // gate-adjacent: n = u*4 + q
        const float* W = dir ? Wih_b : Wih_f;
        Bp[idx] = __float2half((u < 150 && k < 300) ? W[(q * 150 + u) * 300 + k] : 0.f);
    } else if ((idx -= T1) < T2) {
        int l  = idx & 63;
        int r  = idx >> 6;
        int kk = r % 5;  r /= 5;
        int q  = r % 4;  r /= 4;
        int w  = r % 10;
        int dir = r / 10;
        int unit  = w * 16 + (l & 15);
        int kbase = kk * 32 + (l >> 4) * 8;
        const float* W = dir ? Whh_b : Whh_f;
        union { __half h[8]; uint4 u4; } pk;
#pragma unroll
        for (int i = 0; i < 8; ++i) {
            int k = kbase + i;
            pk.h[i] = __float2half((unit < 150 && k < 150)
                                   ? W[(q * 150 + unit) * 150 + k] : 0.f);
        }
        Whhm[idx] = pk.u4;
    } else if ((idx -= T2) < T3) {
        int n = idx;
        int dir = (n >= 640);
        int j2  = n - dir * 640;
        int u = j2 >> 2, q = j2 & 3;
        const float* bb = dir ? b_b : b_f;
        bias_p[n] = (u < 150) ? bb[q * 150 + u] : 0.f;
    }
}

// ---------------- Kernel 1: xg GEMM via MFMA ----------------
// A-RESIDENT (R16) with 4Mx2N wave split: wave tile 32m x 64n (mf=2, nf=4).
// Halves per-wave af ds_reads (2/kb instead of 4) WITHOUT R17's VGPR cliff:
// acc 32 + B(4 rows x depth-2) 32 + af 8 ~ 95 VGPR -> 4 waves/SIMD kept.
// B depth-2 rolling prefetch (10 % 2 == 0 -> phase-stable).
__global__ __launch_bounds__(512) void gemm_xg(const float* __restrict__ x,
                                               const uint4* __restrict__ Bp,
                                               const float* __restrict__ bias_p,
                                               __half* __restrict__ xg) {
    __shared__ uint4 Ash[5120];   // [mt 0..7][kb 0..9][lane 0..63] frag-packed
    const int tid = threadIdx.x;
    const int mb  = blockIdx.x;

    const int w = tid >> 6, l = tid & 63;
    const int wr = w >> 1, wc = w & 1;    // 4 M-waves x 2 N-waves
    const int lr = l & 15, kg = l >> 4;

    // rolling B prefetch: 4 nf rows x 2 deep
    const uint4* pb[4];
#pragma unroll
    for (int nf = 0; nf < 4; ++nf)
        pb[nf] = Bp + (size_t)(wc * 64 + nf * 16 + lr) * 40 + kg;
    uint4 Bv[4][2];
#pragma unroll
    for (int nf = 0; nf < 4; ++nf)
#pragma unroll
        for (int p = 0; p < 2; ++p) Bv[nf][p] = pb[nf][p * 4];

    {   // stage A tile (128 x 320): 4 thr/row, 10 chunks each, frag-packed
        int m   = tid >> 2;
        int chb = (tid & 3) * 10;
        const float* xrow = x + (size_t)(mb * 128 + m) * 300;
        const int mt = m >> 4, ml = m & 15;
        const float4 fz4 = make_float4(0.f, 0.f, 0.f, 0.f);
#pragma unroll
        for (int i = 0; i < 10; ++i) {
            int ch = chb + i, k0 = ch * 8;
            float4 fa = (k0 <= 296) ? *(const float4*)(xrow + k0) : fz4;
            float4 fb = (k0 <= 292) ? *(const float4*)(xrow + k0 + 4) : fz4;
            union { _Float16 h[8]; uint4 u; } pk;
            pk.h[0] = (_Float16)fa.x; pk.h[1] = (_Float16)fa.y;
            pk.h[2] = (_Float16)fa.z; pk.h[3] = (_Float16)fa.w;
            pk.h[4] = (_Float16)fb.x; pk.h[5] = (_Float16)fb.y;
            pk.h[6] = (_Float16)fb.z; pk.h[7] = (_Float16)fb.w;
            Ash[(mt * 10 + (ch >> 2)) * 64 + ((ch & 3) * 16 + ml)] = pk.u;
        }
    }

    __syncthreads();   // A ready (B prologue loads still in flight is fine)

    const int mrow = mb * 128 + wr * 32;
    for (int nb = 0; nb < 10; ++nb) {
        f32x4 acc[2][4];
#pragma unroll
        for (int mf = 0; mf < 2; ++mf)
#pragma unroll
            for (int nf = 0; nf < 4; ++nf) acc[mf][nf] = (f32x4)0.f;

        const uint4* qb[4];
#pragma unroll
        for (int nf = 0; nf < 4; ++nf) qb[nf] = pb[nf] + (size_t)nb * 5120;

#pragma unroll
        for (int kb = 0; kb < 10; ++kb) {
            const int r = kb % 2;      // compile-time; 10 % 2 == 0 -> phase-stable
            uint4 af[2];
#pragma unroll
            for (int mf = 0; mf < 2; ++mf)
                af[mf] = Ash[((wr * 2 + mf) * 10 + kb) * 64 + l];

#pragma unroll
            for (int mf = 0; mf < 2; ++mf) {
                f16x8 av = __builtin_bit_cast(f16x8, af[mf]);
#pragma unroll
                for (int nf = 0; nf < 4; ++nf)
                    acc[mf][nf] = __builtin_amdgcn_mfma_f32_16x16x32_f16(
                        __builtin_bit_cast(f16x8, Bv[nf][r]), av, acc[mf][nf], 0, 0, 0);
            }
            // refill slot r with (nb, kb+2) or (nb+1, kb-8)
            if (kb < 8) {
#pragma unroll
                for (int nf = 0; nf < 4; ++nf) Bv[nf][r] = qb[nf][(kb + 2) * 4];
            } else if (nb < 9) {
#pragma unroll
                for (int nf = 0; nf < 4; ++nf) Bv[nf][r] = qb[nf][5120 + (kb - 8) * 4];
            }
        }

        // epilogue for this nb (next-nb's first B loads already in flight)
        const int ncol = nb * 128 + wc * 64;
#pragma unroll
        for (int mf = 0; mf < 2; ++mf) {
            int m_g = mrow + mf * 16 + lr;
            __half* orow = xg + (size_t)m_g * 1280;
#pragma unroll
            for (int nf = 0; nf < 4; ++nf) {
                int n_g = ncol + nf * 16 + kg * 4;
                float4 bv = *(const float4*)(bias_p + n_g);
                f32x4 v = acc[mf][nf];
                union { __half h[4]; uint2 u; } pk;
                pk.h[0] = __float2half(v[0] + bv.x);
                pk.h[1] = __float2half(v[1] + bv.y);
                pk.h[2] = __float2half(v[2] + bv.z);
                pk.h[3] = __float2half(v[3] + bv.w);
                *(uint2*)(orow + n_g) = pk.u;
            }
        }
    }
}

// ---------------- Kernel 2: MFMA recurrence + pooling (R18-exact, best: 379us) ----------------
__global__ __launch_bounds__(640, 1) void lstm_rec(const uint4* __restrict__ Whhm,
                                                   const __half* __restrict__ xg,
                                                   const int* __restrict__ lens,
                                                   float* __restrict__ out) {
    __shared__ __align__(16) unsigned hbuf[640];   // 2 x 1280 B fragment buffers
    const int tid = threadIdx.x, l = tid & 63, w = tid >> 6;
    const int dir = blockIdx.x & 1, sg = blockIdx.x >> 1;
    const int lr = l & 15, hi = l >> 4;
    const int unit = w * 16 + lr;
    const int b = sg * 4 + hi;

    hbuf[tid < 640 ? tid : 0] = 0u;

    // W fragments consumed directly by MFMA (AGPR-homable, no copy cost)
    uint4 wf[20];
    const uint4* wsrc = Whhm + (size_t)(dir * 10 + w) * 20 * 64 + l;
#pragma unroll
    for (int f = 0; f < 20; ++f) wf[f] = wsrc[(size_t)f * 64];

    float c_s = 0.f, hsum = 0.f, hlast = 0.f;
    const int Lv = lens[b];
    const int mark = dir ? (Tt - Lv) : (Lv - 1);

    // loop-invariant LDS byte offsets
    const int rdoff = (l >> 4) * 64 + ((l >> 2) & 3) * 16;  // + kk*256 immediate
    const int wroff = (w >> 1) * 256 + ((w & 1) * 2 + (lr >> 3)) * 64 + hi * 16 + (lr & 7) * 2;

    const __half* xb = xg + (size_t)b * 512 * 1280 + dir * 640 + unit * 4;

#define T_OF(S) ((dir) ? (511 - ((S) < Tt ? (S) : Tt - 1)) : ((S) < Tt ? (S) : Tt - 1))

    uint2 xq0 = *(const uint2*)(xb + (size_t)T_OF(0) * 1280);
    uint2 xq1 = *(const uint2*)(xb + (size_t)T_OF(1) * 1280);

    __syncthreads();   // once: h zero-init + weight loads visible

    for (int step = 0; step < Tt; ++step) {
        const int P = step & 1;
        uint2 xq2 = *(const uint2*)(xb + (size_t)T_OF(step + 2) * 1280);  // prefetch

        uint4 af[5];
        const char* rbase = (const char*)hbuf + (P * 1280 + rdoff);
#pragma unroll
        for (int kk = 0; kk < 5; ++kk)
            af[kk] = *(const uint4*)(rbase + kk * 256);

        __half2 x01 = __builtin_bit_cast(__half2, xq0.x);
        __half2 x23 = __builtin_bit_cast(__half2, xq0.y);
        f32x4 a0 = (f32x4)0.f, a1 = (f32x4)0.f, a2 = (f32x4)0.f, a3 = (f32x4)0.f;
        a0[0] = __half2float(x01.x);
        a1[0] = __half2float(x01.y);
        a2[0] = __half2float(x23.x);
        a3[0] = __half2float(x23.y);

#pragma unroll
        for (int kk = 0; kk < 5; ++kk) {
            f16x8 hv = __builtin_bit_cast(f16x8, af[kk]);
            a0 = __builtin_amdgcn_mfma_f32_16x16x32_f16(
                hv, __builtin_bit_cast(f16x8, wf[0 * 5 + kk]), a0, 0, 0, 0);
            a1 = __builtin_amdgcn_mfma_f32_16x16x32_f16(
                hv, __builtin_bit_cast(f16x8, wf[1 * 5 + kk]), a1, 0, 0, 0);
            a2 = __builtin_amdgcn_mfma_f32_16x16x32_f16(
                hv, __builtin_bit_cast(f16x8, wf[2 * 5 + kk]), a2, 0, 0, 0);
            a3 = __builtin_amdgcn_mfma_f32_16x16x32_f16(
                hv, __builtin_bit_cast(f16x8, wf[3 * 5 + kk]), a3, 0, 0, 0);
        }

        float i_ = sig2(a0[0]);
        float f_ = sig2(a1[0]);
        float g_ = tanh2(a2[0]);
        float o_ = sig2(a3[0]);
        c_s = f_ * c_s + i_ * g_;
        float h = o_ * tanh2(c_s);
        bool in = dir ? (step >= mark) : (step < Lv);
        if (in) hsum += h;
        if (step == mark) hlast = h;
        *(__half*)((char*)hbuf + ((P ^ 1) * 1280 + wroff)) = __float2half(h);

        xq0 = xq1; xq1 = xq2;
        // T4-analog: wait LDS only; xq2's global load stays in flight.
        asm volatile("s_waitcnt lgkmcnt(0)" ::: "memory");
        __builtin_amdgcn_s_barrier();
    }
#undef T_OF

    if (unit < 150) {
        out[b * 600 + dir * 150 + unit]       = tanh2(hsum / (float)Lv);
        out[b * 600 + 300 + dir * 150 + unit] = tanh2(hlast);
    }
}

// ---------------- launch ----------------
extern "C" void kernel_launch(void* const* d_in, const int* in_sizes, int n_in,
                              void* d_out, int out_size, void* d_ws, size_t ws_size,
                              hipStream_t stream) {
    const float* x     = (const float*)d_in[0];
    const int*   lens  = (const int*)d_in[1];
    const float* Wih_f = (const float*)d_in[2];
    const float* Whh_f = (const float*)d_in[3];
    const float* b_f   = (const float*)d_in[4];
    const float* Wih_b = (const float*)d_in[5];
    const float* Whh_b = (const float*)d_in[6];
    const float* b_b   = (const float*)d_in[7];
    float* out = (float*)d_out;
    char*  ws  = (char*)d_ws;

    __half* Bp     = (__half*)(ws + BP16_OFF);
    uint4*  Whhm   = (uint4*)(ws + WHHM_OFF);
    float*  bias_p = (float*)(ws + BIAS_OFF);
    __half* xg     = (__half*)(ws + XG_OFF);

    {
        int total = 1280 * 320 + 2 * 10 * 4 * 5 * 64 + 1280;
        int blocks = (total + 255) / 256;
        pack_weights<<<blocks, 256, 0, stream>>>(Wih_f, Whh_f, b_f, Wih_b, Whh_b, b_b,
                                                 Bp, Whhm, bias_p);
    }
    {
        gemm_xg<<<512, 512, 0, stream>>>(x, (const uint4*)Bp, bias_p, xg);
    }
    {
        lstm_rec<<<64, 640, 0, stream>>>(Whhm, xg, lens, out);
    }
}

// Round 20
// 518.084 us; speedup vs baseline: 1.1694x; 1.1694x over previous
//
#include <hip/hip_runtime.h>
#include <hip/hip_fp16.h>

#define Tt 512

typedef _Float16 f16x8 __attribute__((ext_vector_type(8)));
typedef float    f32x4 __attribute__((ext_vector_type(4)));

// Workspace byte offsets
#define BP16_OFF 0ul                              // fp16 B panel [1280][320] LINEAR
#define BP16_BYTES (2ul*1280*320)                 // 819,200
#define WHHM_OFF (BP16_OFF + BP16_BYTES)
#define WHHM_BYTES (16ul*2*10*4*5*64)             // 409,600 MFMA W fragments
#define BIAS_OFF (WHHM_OFF + WHHM_BYTES)
#define BIAS_BYTES (4ul*1280)
#define XG_OFF   (4ul*1024*1024)                  // fp16 xg [65536][1280] = 167.8 MB

__device__ __forceinline__ float sig2(float x) {
    return __builtin_amdgcn_rcpf(1.f + __builtin_amdgcn_exp2f(-1.442695041f * x));
}
__device__ __forceinline__ float tanh2(float x) {
    return 2.f * __builtin_amdgcn_rcpf(1.f + __builtin_amdgcn_exp2f(-2.885390082f * x)) - 1.f;
}

// ---------------- Kernel 0: pack weights (R16/R18-exact) ----------------
__global__ void pack_weights(const float* __restrict__ Wih_f, const float* __restrict__ Whh_f,
                             const float* __restrict__ b_f,
                             const float* __restrict__ Wih_b, const float* __restrict__ Whh_b,
                             const float* __restrict__ b_b,
                             __half* __restrict__ Bp, uint4* __restrict__ Whhm,
                             float* __restrict__ bias_p) {
    int idx = blockIdx.x * 256 + threadIdx.x;
    const int T1 = 1280 * 320;
    const int T2 = 2 * 10 * 4 * 5 * 64;
    const int T3 = 1280;
    if (idx < T1) {
        int n = idx / 320, k = idx % 320;
        int dir = (n >= 640);
        int j2  = n - dir * 640;
        int u = j2 >> 2, q = j2 & 3;       // gate-adjacent: n = u*4 + q
        const float* W = dir ? Wih_b : Wih_f;
        Bp[idx] = __float2half((u < 150 && k < 300) ? W[(q * 150 + u) * 300 + k] : 0.f);
    } else if ((idx -= T1) < T2) {
        int l  = idx & 63;
        int r  = idx >> 6;
        int kk = r % 5;  r /= 5;
        int q  = r % 4;  r /= 4;
        int w  = r % 10;
        int dir = r / 10;
        int unit  = w * 16 + (l & 15);
        int kbase = kk * 32 + (l >> 4) * 8;
        const float* W = dir ? Whh_b : Whh_f;
        union { __half h[8]; uint4 u4; } pk;
#pragma unroll
        for (int i = 0; i < 8; ++i) {
            int k = kbase + i;
            pk.h[i] = __float2half((unit < 150 && k < 150)
                                   ? W[(q * 150 + unit) * 150 + k] : 0.f);
        }
        Whhm[idx] = pk.u4;
    } else if ((idx -= T2) < T3) {
        int n = idx;
        int dir = (n >= 640);
        int j2  = n - dir * 640;
        int u = j2 >> 2, q = j2 & 3;
        const float* bb = dir ? b_b : b_f;
        bias_p[n] = (u < 150) ? bb[q * 150 + u] : 0.f;
    }
}

// ---------------- Kernel 1: xg GEMM via MFMA (R16-exact, best measured) ----------------
// A-RESIDENT: 512 blocks (one 128-row A tile each, HBM-read ONCE), A staged
// fp32->fp16 into FRAGMENT-PACKED LDS (conflict-free ds_read_b128). B streamed
// from L2 with 5-deep rolling prefetch (depth 5 divides 10 -> phase-stable).
// 8 waves = 2 wr x 4 wc, wave tile 64m x 32n, nb loop covers N=1280.
__global__ __launch_bounds__(512) void gemm_xg(const float* __restrict__ x,
                                               const uint4* __restrict__ Bp,
                                               const float* __restrict__ bias_p,
                                               __half* __restrict__ xg) {
    __shared__ uint4 Ash[5120];   // [mt 0..7][kb 0..9][lane 0..63]
    const int tid = threadIdx.x;
    const int mb  = blockIdx.x;

    const int w = tid >> 6, l = tid & 63;
    const int wr = w >> 2, wc = w & 3;    // 2 M-waves x 4 N-waves
    const int lr = l & 15, kg = l >> 4;

    // rolling B prefetch (lane-fixed n rows, chunk index = kb*4 + kg)
    const int nl0 = wc * 32 + lr;
    const uint4* pb0 = Bp + (size_t)nl0 * 40 + kg;
    const uint4* pb1 = pb0 + 16 * 40;
    uint4 B0[5], B1[5];
#pragma unroll
    for (int p = 0; p < 5; ++p) { B0[p] = pb0[p * 4]; B1[p] = pb1[p * 4]; }

    {   // stage A tile (128 x 320): 4 thr/row, 10 chunks each, frag-packed
        int m   = tid >> 2;
        int chb = (tid & 3) * 10;
        const float* xrow = x + (size_t)(mb * 128 + m) * 300;
        const int mt = m >> 4, ml = m & 15;
        const float4 fz4 = make_float4(0.f, 0.f, 0.f, 0.f);
#pragma unroll
        for (int i = 0; i < 10; ++i) {
            int ch = chb + i, k0 = ch * 8;
            float4 fa = (k0 <= 296) ? *(const float4*)(xrow + k0) : fz4;
            float4 fb = (k0 <= 292) ? *(const float4*)(xrow + k0 + 4) : fz4;
            union { _Float16 h[8]; uint4 u; } pk;
            pk.h[0] = (_Float16)fa.x; pk.h[1] = (_Float16)fa.y;
            pk.h[2] = (_Float16)fa.z; pk.h[3] = (_Float16)fa.w;
            pk.h[4] = (_Float16)fb.x; pk.h[5] = (_Float16)fb.y;
            pk.h[6] = (_Float16)fb.z; pk.h[7] = (_Float16)fb.w;
            Ash[(mt * 10 + (ch >> 2)) * 64 + ((ch & 3) * 16 + ml)] = pk.u;
        }
    }

    __syncthreads();   // A ready (B prologue loads still in flight is fine)

    const int mrow = mb * 128 + wr * 64;
    for (int nb = 0; nb < 10; ++nb) {
        f32x4 acc[4][2];
#pragma unroll
        for (int mf = 0; mf < 4; ++mf) { acc[mf][0] = (f32x4)0.f; acc[mf][1] = (f32x4)0.f; }

        const uint4* qb0 = pb0 + (size_t)nb * 5120;
        const uint4* qb1 = pb1 + (size_t)nb * 5120;

#pragma unroll
        for (int kb = 0; kb < 10; ++kb) {
            const int r = kb % 5;      // compile-time; 10 % 5 == 0 -> phase-stable
            uint4 af[4];
#pragma unroll
            for (int mf = 0; mf < 4; ++mf)
                af[mf] = Ash[((wr * 4 + mf) * 10 + kb) * 64 + l];

            f16x8 b0v = __builtin_bit_cast(f16x8, B0[r]);
            f16x8 b1v = __builtin_bit_cast(f16x8, B1[r]);
#pragma unroll
            for (int mf = 0; mf < 4; ++mf) {
                f16x8 av = __builtin_bit_cast(f16x8, af[mf]);
                acc[mf][0] = __builtin_amdgcn_mfma_f32_16x16x32_f16(b0v, av, acc[mf][0], 0, 0, 0);
                acc[mf][1] = __builtin_amdgcn_mfma_f32_16x16x32_f16(b1v, av, acc[mf][1], 0, 0, 0);
            }
            // refill slot r with (nb, kb+5) or (nb+1, kb-5)
            if (kb < 5) {
                B0[r] = qb0[(kb + 5) * 4];
                B1[r] = qb1[(kb + 5) * 4];
            } else if (nb < 9) {
                B0[r] = qb0[5120 + (kb - 5) * 4];
                B1[r] = qb1[5120 + (kb - 5) * 4];
            }
        }

        // epilogue for this nb (next-nb's first B loads already in flight)
        const int ncol = nb * 128 + wc * 32;
#pragma unroll
        for (int mf = 0; mf < 4; ++mf) {
            int m_g = mrow + mf * 16 + lr;
            __half* orow = xg + (size_t)m_g * 1280;
#pragma unroll
            for (int nf = 0; nf < 2; ++nf) {
                int n_g = ncol + nf * 16 + kg * 4;
                float4 bv = *(const float4*)(bias_p + n_g);
                f32x4 v = acc[mf][nf];
                union { __half h[4]; uint2 u; } pk;
                pk.h[0] = __float2half(v[0] + bv.x);
                pk.h[1] = __float2half(v[1] + bv.y);
                pk.h[2] = __float2half(v[2] + bv.z);
                pk.h[3] = __float2half(v[3] + bv.w);
                *(uint2*)(orow + n_g) = pk.u;
            }
        }
    }
}

// ---------------- Kernel 2: MFMA recurrence + pooling (R18-exact, best: 379us) ----------------
// R8 structure + T4-analog barrier: raw s_barrier with lgkmcnt(0)-only wait,
// so the 2-step-ahead xq global prefetch stays in flight across barriers
// (__syncthreads' vmcnt(0) drain was defeating it).
__global__ __launch_bounds__(640, 1) void lstm_rec(const uint4* __restrict__ Whhm,
                                                   const __half* __restrict__ xg,
                                                   const int* __restrict__ lens,
                                                   float* __restrict__ out) {
    __shared__ __align__(16) unsigned hbuf[640];   // 2 x 1280 B fragment buffers
    const int tid = threadIdx.x, l = tid & 63, w = tid >> 6;
    const int dir = blockIdx.x & 1, sg = blockIdx.x >> 1;
    const int lr = l & 15, hi = l >> 4;
    const int unit = w * 16 + lr;
    const int b = sg * 4 + hi;

    hbuf[tid < 640 ? tid : 0] = 0u;

    // W fragments consumed directly by MFMA (AGPR-homable, no copy cost)
    uint4 wf[20];
    const uint4* wsrc = Whhm + (size_t)(dir * 10 + w) * 20 * 64 + l;
#pragma unroll
    for (int f = 0; f < 20; ++f) wf[f] = wsrc[(size_t)f * 64];

    float c_s = 0.f, hsum = 0.f, hlast = 0.f;
    const int Lv = lens[b];
    const int mark = dir ? (Tt - Lv) : (Lv - 1);

    // loop-invariant LDS byte offsets
    const int rdoff = (l >> 4) * 64 + ((l >> 2) & 3) * 16;  // + kk*256 immediate
    const int wroff = (w >> 1) * 256 + ((w & 1) * 2 + (lr >> 3)) * 64 + hi * 16 + (lr & 7) * 2;

    const __half* xb = xg + (size_t)b * 512 * 1280 + dir * 640 + unit * 4;

#define T_OF(S) ((dir) ? (511 - ((S) < Tt ? (S) : Tt - 1)) : ((S) < Tt ? (S) : Tt - 1))

    uint2 xq0 = *(const uint2*)(xb + (size_t)T_OF(0) * 1280);
    uint2 xq1 = *(const uint2*)(xb + (size_t)T_OF(1) * 1280);

    __syncthreads();   // once: h zero-init + weight loads visible

    for (int step = 0; step < Tt; ++step) {
        const int P = step & 1;
        uint2 xq2 = *(const uint2*)(xb + (size_t)T_OF(step + 2) * 1280);  // prefetch

        uint4 af[5];
        const char* rbase = (const char*)hbuf + (P * 1280 + rdoff);
#pragma unroll
        for (int kk = 0; kk < 5; ++kk)
            af[kk] = *(const uint4*)(rbase + kk * 256);

        __half2 x01 = __builtin_bit_cast(__half2, xq0.x);
        __half2 x23 = __builtin_bit_cast(__half2, xq0.y);
        f32x4 a0 = (f32x4)0.f, a1 = (f32x4)0.f, a2 = (f32x4)0.f, a3 = (f32x4)0.f;
        a0[0] = __half2float(x01.x);
        a1[0] = __half2float(x01.y);
        a2[0] = __half2float(x23.x);
        a3[0] = __half2float(x23.y);

#pragma unroll
        for (int kk = 0; kk < 5; ++kk) {
            f16x8 hv = __builtin_bit_cast(f16x8, af[kk]);
            a0 = __builtin_amdgcn_mfma_f32_16x16x32_f16(
                hv, __builtin_bit_cast(f16x8, wf[0 * 5 + kk]), a0, 0, 0, 0);
            a1 = __builtin_amdgcn_mfma_f32_16x16x32_f16(
                hv, __builtin_bit_cast(f16x8, wf[1 * 5 + kk]), a1, 0, 0, 0);
            a2 = __builtin_amdgcn_mfma_f32_16x16x32_f16(
                hv, __builtin_bit_cast(f16x8, wf[2 * 5 + kk]), a2, 0, 0, 0);
            a3 = __builtin_amdgcn_mfma_f32_16x16x32_f16(
                hv, __builtin_bit_cast(f16x8, wf[3 * 5 + kk]), a3, 0, 0, 0);
        }

        float i_ = sig2(a0[0]);
        float f_ = sig2(a1[0]);
        float g_ = tanh2(a2[0]);
        float o_ = sig2(a3[0]);
        c_s = f_ * c_s + i_ * g_;
        float h = o_ * tanh2(c_s);
        bool in = dir ? (step >= mark) : (step < Lv);
        if (in) hsum += h;
        if (step == mark) hlast = h;
        *(__half*)((char*)hbuf + ((P ^ 1) * 1280 + wroff)) = __float2half(h);

        xq0 = xq1; xq1 = xq2;
        // T4-analog: wait LDS only; xq2's global load stays in flight.
        asm volatile("s_waitcnt lgkmcnt(0)" ::: "memory");
        __builtin_amdgcn_s_barrier();
    }
#undef T_OF

    if (unit < 150) {
        out[b * 600 + dir * 150 + unit]       = tanh2(hsum / (float)Lv);
        out[b * 600 + 300 + dir * 150 + unit] = tanh2(hlast);
    }
}

// ---------------- launch ----------------
extern "C" void kernel_launch(void* const* d_in, const int* in_sizes, int n_in,
                              void* d_out, int out_size, void* d_ws, size_t ws_size,
                              hipStream_t stream) {
    const float* x     = (const float*)d_in[0];
    const int*   lens  = (const int*)d_in[1];
    const float* Wih_f = (const float*)d_in[2];
    const float* Whh_f = (const float*)d_in[3];
    const float* b_f   = (const float*)d_in[4];
    const float* Wih_b = (const float*)d_in[5];
    const float* Whh_b = (const float*)d_in[6];
    const float* b_b   = (const float*)d_in[7];
    float* out = (float*)d_out;
    char*  ws  = (char*)d_ws;

    __half* Bp     = (__half*)(ws + BP16_OFF);
    uint4*  Whhm   = (uint4*)(ws + WHHM_OFF);
    float*  bias_p = (float*)(ws + BIAS_OFF);
    __half* xg     = (__half*)(ws + XG_OFF);

    {
        int total = 1280 * 320 + 2 * 10 * 4 * 5 * 64 + 1280;
        int blocks = (total + 255) / 256;
        pack_weights<<<blocks, 256, 0, stream>>>(Wih_f, Whh_f, b_f, Wih_b, Whh_b, b_b,
                                                 Bp, Whhm, bias_p);
    }
    {
        gemm_xg<<<512, 512, 0, stream>>>(x, (const uint4*)Bp, bias_p, xg);
    }
    {
        lstm_rec<<<64, 640, 0, stream>>>(Whhm, xg, lens, out);
    }
}